// Round 8
// baseline (662.048 us; speedup 1.0000x reference)
//
#include <hip/hip_runtime.h>
#include <cstddef>
#include <cstdint>

#define SEQ   2048
#define DIM   64
#define NHEAD 32
#define BM    128
#define BN    128
#define NT    (SEQ / BN)
#define WLD   68            // padded stride (floats) for [.][64] f32 LDS tiles
#define LOG2E 1.44269504088896340736f

typedef __attribute__((ext_vector_type(8))) short short8v;  // 8 bf16 = one MFMA A/B frag
typedef __attribute__((ext_vector_type(4))) float f32x4;    // MFMA accumulator

__device__ __forceinline__ float fexp2(float x) { return __builtin_amdgcn_exp2f(x); }

// f32 -> bf16 round-to-nearest-even
__device__ __forceinline__ unsigned short f2bf(float x) {
    union { float f; unsigned u; } v; v.f = x;
    unsigned r = v.u + 0x7FFFu + ((v.u >> 16) & 1u);
    return (unsigned short)(r >> 16);
}
__device__ __forceinline__ float bf2f(unsigned short h) {
    union { unsigned u; float f; } v; v.u = ((unsigned)h) << 16;
    return v.f;
}

// async global->LDS, 16B/lane; LDS dest = wave-uniform base + lane*16
__device__ __forceinline__ void gl_lds16(const void* g, void* l) {
    __builtin_amdgcn_global_load_lds(
        (const __attribute__((address_space(1))) unsigned int*)g,
        (__attribute__((address_space(3))) unsigned int*)l,
        16, 0, 0);
}

// ---------------------------------------------------------------------------
// K1: kf = relu(k @ W^T) f32, split kf = kh + kl (bf16 pair), layout [head][s][f].
// (unscaled; the log2e factor is folded into the q side only)
// ---------------------------------------------------------------------------
__global__ __launch_bounds__(256) void kfsplit_kernel(const float* __restrict__ kin,
                                                      const float* __restrict__ W,
                                                      unsigned short* __restrict__ khg,
                                                      unsigned short* __restrict__ klg)
{
    __shared__ __align__(16) float Ws[64 * WLD];
    const int tid  = threadIdx.x;
    const int head = blockIdx.x >> 4;
    const int r0   = (blockIdx.x & 15) * BM;

    {   // stage W [64][WLD]
        const int f = tid >> 2, cc = (tid & 3) * 16;
        const float* gw = W + f * DIM + cc;
        #pragma unroll
        for (int kk = 0; kk < 4; ++kk)
            *reinterpret_cast<float4*>(&Ws[f * WLD + cc + kk * 4]) =
                *reinterpret_cast<const float4*>(gw + kk * 4);
    }
    __syncthreads();

    const int lane = tid & 63;
    const int wid  = tid >> 6;
    const float* kb = kin + ((size_t)head * SEQ + r0) * DIM;

    float acc0[16], acc1[16];
    #pragma unroll
    for (int j = 0; j < 16; ++j) { acc0[j] = 0.f; acc1[j] = 0.f; }

    for (int d4 = 0; d4 < 16; ++d4) {
        const float4 x0 = *reinterpret_cast<const float4*>(kb + (size_t)lane * DIM + d4 * 4);
        const float4 x1 = *reinterpret_cast<const float4*>(kb + (size_t)(64 + lane) * DIM + d4 * 4);
        #pragma unroll
        for (int j = 0; j < 16; ++j) {
            const float4 w4 = *reinterpret_cast<const float4*>(&Ws[(wid * 16 + j) * WLD + d4 * 4]);
            acc0[j] = fmaf(x0.x, w4.x, fmaf(x0.y, w4.y, fmaf(x0.z, w4.z, fmaf(x0.w, w4.w, acc0[j]))));
            acc1[j] = fmaf(x1.x, w4.x, fmaf(x1.y, w4.y, fmaf(x1.z, w4.z, fmaf(x1.w, w4.w, acc1[j]))));
        }
    }

#define SPLIT_ROW(ACC, ROWOFF)                                                          \
    do {                                                                                \
        unsigned hp[8], lp[8];                                                          \
        _Pragma("unroll")                                                               \
        for (int j2 = 0; j2 < 8; ++j2) {                                                \
            const float kf0 = fmaxf(ACC[2 * j2], 0.f);                                  \
            const float kf1 = fmaxf(ACC[2 * j2 + 1], 0.f);                              \
            const unsigned short h0 = f2bf(kf0), h1 = f2bf(kf1);                        \
            const unsigned short l0 = f2bf(kf0 - bf2f(h0));                             \
            const unsigned short l1 = f2bf(kf1 - bf2f(h1));                             \
            hp[j2] = (unsigned)h0 | ((unsigned)h1 << 16);                               \
            lp[j2] = (unsigned)l0 | ((unsigned)l1 << 16);                               \
        }                                                                               \
        unsigned short* dh = khg + ((size_t)head * SEQ + r0 + (ROWOFF)) * DIM + wid * 16; \
        unsigned short* dl = klg + ((size_t)head * SEQ + r0 + (ROWOFF)) * DIM + wid * 16; \
        uint4 a, b;                                                                     \
        a.x = hp[0]; a.y = hp[1]; a.z = hp[2]; a.w = hp[3];                             \
        b.x = hp[4]; b.y = hp[5]; b.z = hp[6]; b.w = hp[7];                             \
        *reinterpret_cast<uint4*>(dh) = a; *reinterpret_cast<uint4*>(dh + 8) = b;       \
        a.x = lp[0]; a.y = lp[1]; a.z = lp[2]; a.w = lp[3];                             \
        b.x = lp[4]; b.y = lp[5]; b.z = lp[6]; b.w = lp[7];                             \
        *reinterpret_cast<uint4*>(dl) = a; *reinterpret_cast<uint4*>(dl + 8) = b;       \
    } while (0)

    SPLIT_ROW(acc0, lane);
    SPLIT_ROW(acc1, 64 + lane);
#undef SPLIT_ROW
}

// ---------------------------------------------------------------------------
// K2 v3: operand-swapped MFMA — compute S^T tiles: mfma(A=kh, B=qh).
// D: col(lane&15) = q-row, reg-quad = 4 consecutive kf-cols.
//  -> softmax rows live per-lane (in-register max/sum, 2-step shfl at end)
//  -> pass-2 stores are float4 (4 consecutive cols per lane)
// qf is pre-scaled by log2e so all exponentials are single v_exp_f32 (exp2).
// Double-buffered async kh/kl staging via global_load_lds (pre-swizzled src).
// LDS map unchanged from v2 (67584 B).
// ---------------------------------------------------------------------------
__global__ __launch_bounds__(256, 2) void attn_kernel(const float* __restrict__ q,
                                                      const float* __restrict__ W,
                                                      const unsigned short* __restrict__ khg,
                                                      const unsigned short* __restrict__ klg,
                                                      float* __restrict__ out)
{
    __shared__ __align__(16) unsigned char lds_raw[67584];
    float* Ws   = (float*)lds_raw;                  // [64][WLD] phase 0
    float* qf   = (float*)(lds_raw + 32768);        // [128][WLD] phase 0
    float* mbuf = (float*)(lds_raw + 65536);        // [4][64]
    float* lbuf = (float*)(lds_raw + 66560);        // [4][64]

    const int tid  = threadIdx.x;
    const int head = blockIdx.x >> 4;
    const int r0   = (blockIdx.x & 15) * BM;
    const int lane = tid & 63;
    const int wid  = tid >> 6;

    const size_t khead_b = (size_t)head * SEQ * DIM * 2;
    const unsigned char* gkh = (const unsigned char*)khg + khead_b;
    const unsigned char* gkl = (const unsigned char*)klg + khead_b;

#define STAGE(BUF, T)                                                                   \
    do {                                                                                \
        const unsigned char* skh = gkh + (size_t)(T) * (BN * DIM * 2);                  \
        const unsigned char* skl = gkl + (size_t)(T) * (BN * DIM * 2);                  \
        unsigned char* lkh = lds_raw + (BUF) * 32768;                                   \
        unsigned char* lkl = lkh + 16384;                                               \
        _Pragma("unroll")                                                               \
        for (int i_ = 0; i_ < 4; ++i_) {                                                \
            const unsigned o_   = wid * 4096 + i_ * 1024 + lane * 16;                   \
            const unsigned row_ = o_ >> 7;                                              \
            const unsigned u_   = (o_ & ~127u) | ((o_ & 127u) ^ ((row_ & 7u) << 4));    \
            gl_lds16(skh + u_, lkh + wid * 4096 + i_ * 1024);                           \
            gl_lds16(skl + u_, lkl + wid * 4096 + i_ * 1024);                           \
        }                                                                               \
    } while (0)

    // ---- phase 0a: stage W into Ws ----
    {
        const int f = tid >> 2, cc = (tid & 3) * 16;
        const float* gw = W + f * DIM + cc;
        #pragma unroll
        for (int kk = 0; kk < 4; ++kk)
            *reinterpret_cast<float4*>(&Ws[f * WLD + cc + kk * 4]) =
                *reinterpret_cast<const float4*>(gw + kk * 4);
    }
    __syncthreads();

    // ---- phase 0b: qf = relu(q W^T) * log2e into LDS ----
    {
        const float* qb = q + ((size_t)head * SEQ + r0) * DIM;
        float a0[16], a1[16];
        #pragma unroll
        for (int j = 0; j < 16; ++j) { a0[j] = 0.f; a1[j] = 0.f; }
        for (int d4 = 0; d4 < 16; ++d4) {
            const float4 x0 = *reinterpret_cast<const float4*>(qb + (size_t)lane * DIM + d4 * 4);
            const float4 x1 = *reinterpret_cast<const float4*>(qb + (size_t)(64 + lane) * DIM + d4 * 4);
            #pragma unroll
            for (int j = 0; j < 16; ++j) {
                const float4 w4 = *reinterpret_cast<const float4*>(&Ws[(wid * 16 + j) * WLD + d4 * 4]);
                a0[j] = fmaf(x0.x, w4.x, fmaf(x0.y, w4.y, fmaf(x0.z, w4.z, fmaf(x0.w, w4.w, a0[j]))));
                a1[j] = fmaf(x1.x, w4.x, fmaf(x1.y, w4.y, fmaf(x1.z, w4.z, fmaf(x1.w, w4.w, a1[j]))));
            }
        }
        #pragma unroll
        for (int j = 0; j < 16; ++j) {
            qf[(size_t)lane * WLD + wid * 16 + j]        = fmaxf(a0[j] * LOG2E, 0.f);
            qf[(size_t)(64 + lane) * WLD + wid * 16 + j] = fmaxf(a1[j] * LOG2E, 0.f);
        }
    }
    __syncthreads();          // qf ready; Ws dead

    STAGE(0, 0);              // prefetch tile 0 into buf0

    // ---- phase 0c: persistent q frags (B-operand): row = wrow+cf*16+lr ----
    const int lr = lane & 15, lh = lane >> 4;
    const int wrow = (wid >> 1) * 64, wcol = (wid & 1) * 64;
    short8v qh[4][2], ql[4][2];
    #pragma unroll
    for (int cf = 0; cf < 4; ++cf)
        #pragma unroll
        for (int ks = 0; ks < 2; ++ks) {
            const float* src = &qf[(size_t)(wrow + cf * 16 + lr) * WLD + ks * 32 + lh * 8];
            short8v h, l;
            #pragma unroll
            for (int e = 0; e < 8; ++e) {
                const float x = src[e];
                const unsigned short hh = f2bf(x);
                h[e] = (short)hh;
                l[e] = (short)f2bf(x - bf2f(hh));
            }
            qh[cf][ks] = h;
            ql[cf][ks] = l;
        }
    __syncthreads();          // qf dead; buf0 drained

    // A-operand (kh/kl) reads + swapped MFMA: acc[rf][cf], rf = kf-col subtile
#define COMPUTE_ACC(BUF)                                                                  \
    do {                                                                                  \
        const unsigned char* khb = lds_raw + (BUF) * 32768;                               \
        const unsigned char* klb = khb + 16384;                                           \
        _Pragma("unroll")                                                                 \
        for (int rf = 0; rf < 4; ++rf) {                                                  \
            const int c  = wcol + rf * 16 + lr;                                           \
            const int rb = c * 128 + lh * 16;                                             \
            const int sw = (c & 7) << 4;                                                  \
            const short8v ah0 = *reinterpret_cast<const short8v*>(khb + ((rb) ^ sw));     \
            const short8v ah1 = *reinterpret_cast<const short8v*>(khb + ((rb + 64) ^ sw));\
            const short8v al0 = *reinterpret_cast<const short8v*>(klb + ((rb) ^ sw));     \
            const short8v al1 = *reinterpret_cast<const short8v*>(klb + ((rb + 64) ^ sw));\
            _Pragma("unroll")                                                             \
            for (int cf = 0; cf < 4; ++cf) {                                              \
                f32x4 a = acc[rf][cf];                                                    \
                a = __builtin_amdgcn_mfma_f32_16x16x32_bf16(ah0, qh[cf][0], a, 0, 0, 0);  \
                a = __builtin_amdgcn_mfma_f32_16x16x32_bf16(ah0, ql[cf][0], a, 0, 0, 0);  \
                a = __builtin_amdgcn_mfma_f32_16x16x32_bf16(al0, qh[cf][0], a, 0, 0, 0);  \
                a = __builtin_amdgcn_mfma_f32_16x16x32_bf16(ah1, qh[cf][1], a, 0, 0, 0);  \
                a = __builtin_amdgcn_mfma_f32_16x16x32_bf16(ah1, ql[cf][1], a, 0, 0, 0);  \
                a = __builtin_amdgcn_mfma_f32_16x16x32_bf16(al1, qh[cf][1], a, 0, 0, 0);  \
                acc[rf][cf] = a;                                                          \
            }                                                                             \
        }                                                                                 \
    } while (0)

    // per-lane softmax state: 4 q-rows (cf), scores in exp2 domain
    float m4[4], l4[4];
    #pragma unroll
    for (int i = 0; i < 4; ++i) { m4[i] = -INFINITY; l4[i] = 0.f; }

    // ============================ PASS 1: row stats ============================
    {
        int cur = 0;
        for (int t = 0; t < NT; ++t) {
            if (t + 1 < NT) STAGE(cur ^ 1, t + 1);
            f32x4 acc[4][4] = {};
            COMPUTE_ACC(cur);
            #pragma unroll
            for (int cf = 0; cf < 4; ++cf) {
                float tm = fmaxf(fmaxf(acc[0][cf][0], acc[0][cf][1]),
                                 fmaxf(acc[0][cf][2], acc[0][cf][3]));
                #pragma unroll
                for (int rf = 1; rf < 4; ++rf)
                    tm = fmaxf(tm, fmaxf(fmaxf(acc[rf][cf][0], acc[rf][cf][1]),
                                         fmaxf(acc[rf][cf][2], acc[rf][cf][3])));
                const float mn = fmaxf(m4[cf], tm);
                float p = 0.f;
                #pragma unroll
                for (int rf = 0; rf < 4; ++rf) {
                    p += fexp2(acc[rf][cf][0] - mn);
                    p += fexp2(acc[rf][cf][1] - mn);
                    p += fexp2(acc[rf][cf][2] - mn);
                    p += fexp2(acc[rf][cf][3] - mn);
                }
                l4[cf] = l4[cf] * fexp2(m4[cf] - mn) + p;
                m4[cf] = mn;
            }
            __syncthreads();
            cur ^= 1;
        }
    }

    STAGE(0, 0);               // prefetch pass-2 tile 0 (overlaps the reduce)

    // cross-lane reduce over the 4 lh groups holding the same q-rows
    #pragma unroll
    for (int s = 16; s <= 32; s <<= 1) {
        #pragma unroll
        for (int i = 0; i < 4; ++i) {
            const float m2 = __shfl_xor(m4[i], s);
            const float l2 = __shfl_xor(l4[i], s);
            const float mn = fmaxf(m4[i], m2);
            l4[i] = l4[i] * fexp2(m4[i] - mn) + l2 * fexp2(m2 - mn);
            m4[i] = mn;
        }
    }

    // cross-wave combine: waves wid and wid^1 each saw half the kf-cols
    if (lh == 0) {
        #pragma unroll
        for (int i = 0; i < 4; ++i) {
            mbuf[wid * 64 + i * 16 + lr] = m4[i];
            lbuf[wid * 64 + i * 16 + lr] = l4[i];
        }
    }
    __syncthreads();           // stats visible; pass-2 prefetch drained
    {
        const int pw = wid ^ 1;
        #pragma unroll
        for (int i = 0; i < 4; ++i) {
            const float m2 = mbuf[pw * 64 + i * 16 + lr];
            const float l2 = lbuf[pw * 64 + i * 16 + lr];
            const float mn = fmaxf(m4[i], m2);
            l4[i] = l4[i] * fexp2(m4[i] - mn) + l2 * fexp2(m2 - mn);
            m4[i] = mn;
        }
    }
    #pragma unroll
    for (int i = 0; i < 4; ++i) l4[i] = 1.0f / l4[i];

    // ============================ PASS 2: write softmax ========================
    float* outp = out + ((size_t)head * SEQ + r0) * SEQ;
    {
        int cur = 0;
        for (int t = 0; t < NT; ++t) {
            if (t + 1 < NT) STAGE(cur ^ 1, t + 1);
            f32x4 acc[4][4] = {};
            COMPUTE_ACC(cur);
            const int col0 = t * BN + wcol + lh * 4;
            #pragma unroll
            for (int cf = 0; cf < 4; ++cf) {
                const float m = m4[cf], ri = l4[cf];
                float* rowp = outp + (size_t)(wrow + cf * 16 + lr) * SEQ + col0;
                #pragma unroll
                for (int rf = 0; rf < 4; ++rf) {
                    float4 o;
                    o.x = fexp2(acc[rf][cf][0] - m) * ri;
                    o.y = fexp2(acc[rf][cf][1] - m) * ri;
                    o.z = fexp2(acc[rf][cf][2] - m) * ri;
                    o.w = fexp2(acc[rf][cf][3] - m) * ri;
                    *reinterpret_cast<float4*>(rowp + rf * 16) = o;
                }
            }
            __syncthreads();
            cur ^= 1;
        }
    }
#undef STAGE
#undef COMPUTE_ACC
}

// ---------------------------------------------------------------------------
// kh/kl (16 MiB total) go to d_ws when big enough; else they exactly fill the
// attn_output region of d_out (read by attn_kernel, then overwritten by the
// v copy — stream-ordered). attn_output == v (softmax rows sum to 1).
// ---------------------------------------------------------------------------
extern "C" void kernel_launch(void* const* d_in, const int* in_sizes, int n_in,
                              void* d_out, int out_size, void* d_ws, size_t ws_size,
                              hipStream_t stream)
{
    const float* q = (const float*)d_in[0];
    const float* k = (const float*)d_in[1];
    const float* v = (const float*)d_in[2];
    const float* W = (const float*)d_in[3];
    float* out = (float*)d_out;

    const size_t nkf = (size_t)NHEAD * SEQ * DIM;   // 4,194,304 elements
    unsigned short* kh;
    if (d_ws != nullptr && ws_size >= nkf * 4u) {
        kh = (unsigned short*)d_ws;
    } else {
        kh = (unsigned short*)out;
    }
    unsigned short* kl = kh + nkf;
    float* attn = out + nkf;

    kfsplit_kernel<<<NHEAD * (SEQ / BM), 256, 0, stream>>>(k, W, kh, kl);
    attn_kernel<<<NHEAD * (SEQ / BM), 256, 0, stream>>>(q, W, kh, kl, attn);

    hipMemcpyAsync((void*)out, (const void*)v, nkf * sizeof(float),
                   hipMemcpyDeviceToDevice, stream);
}